// Round 5
// baseline (622.325 us; speedup 1.0000x reference)
//
#include <hip/hip_runtime.h>

typedef _Float16 f16;
typedef _Float16 f16x8 __attribute__((ext_vector_type(8)));
typedef _Float16 f16x4 __attribute__((ext_vector_type(4)));
typedef float f32x4 __attribute__((ext_vector_type(4)));

#define TD 512
#define TDH 2048

// tanh-form GELU: x * sigmoid(1.595769122*x + 0.0713548162*x^3)
__device__ __forceinline__ float gelu_fast(float x) {
  float u = x * fmaf(x * x, 0.0713548162f, 1.595769122f);
  float e = __expf(-u);
  return x * __builtin_amdgcn_rcpf(1.0f + e);
}

__device__ __forceinline__ void glds16(const f16* g, f16* l) {
  __builtin_amdgcn_global_load_lds(
      (const __attribute__((address_space(1))) void*)g,
      (__attribute__((address_space(3))) void*)l, 16, 0, 0);
}

// fused waitcnt+barrier, single asm block => compiler cannot interleave
#define WAITB(N) \
  asm volatile("s_waitcnt vmcnt(" #N ")\n\ts_barrier" ::: "memory")
#define DRAINB() \
  asm volatile("s_waitcnt lgkmcnt(0)\n\ts_barrier" ::: "memory")

__global__ __launch_bounds__(256) void k_conv_x(f16* __restrict__ dst,
                                                const float* __restrict__ src,
                                                int n4) {
  int i = blockIdx.x * 256 + threadIdx.x;
  if (i >= n4) return;
  float4 v = ((const float4*)src)[i];
  f16x4 o = {(f16)v.x, (f16)v.y, (f16)v.z, (f16)v.w};
  ((f16x4*)dst)[i] = o;
}

// Tiled transpose: dst[c*R + r] = src[r*C + c], both sides coalesced.
__global__ void k_trans(f16* __restrict__ dst, const float* __restrict__ src,
                        int R, int C) {
  __shared__ float t[32][33];
  const int bx = blockIdx.x, by = blockIdx.y;
  const int tx = threadIdx.x, ty = threadIdx.y;
#pragma unroll
  for (int s = 0; s < 32; s += 8)
    t[ty + s][tx] = src[(size_t)(by * 32 + ty + s) * C + bx * 32 + tx];
  __syncthreads();
#pragma unroll
  for (int s = 0; s < 32; s += 8)
    dst[(size_t)(bx * 32 + ty + s) * R + by * 32 + tx] = (f16)t[tx][ty + s];
}

// wdT[128][512]: n=e*8+r for n<24 else 0 ; src wd[3][512][8]
__global__ __launch_bounds__(256) void k_wdT(f16* __restrict__ dst,
                                             const float* __restrict__ wd) {
  int i = blockIdx.x * 256 + threadIdx.x;
  int n = i >> 9, k = i & 511;
  float v = (n < 24) ? wd[(size_t)((n >> 3) * 512 + k) * 8 + (n & 7)] : 0.0f;
  dst[i] = (f16)v;
}

// wuT[512][32]: wuT[d][e*8+r] = wu[e][r][d] for er<24 else 0
__global__ __launch_bounds__(256) void k_wuT(f16* __restrict__ dst,
                                             const float* __restrict__ wu) {
  int i = blockIdx.x * 256 + threadIdx.x;
  int d = i >> 5, er = i & 31;
  float v = (er < 24) ? wu[(size_t)(er >> 3) * 4096 + (er & 7) * 512 + d] : 0.0f;
  dst[i] = (f16)v;
}

// ---------------------------------------------------------------------------
// 256x256 tile, BK=32, 8 waves (2M x 4N), per-wave 128x64 (8x4 frags).
// Triple-buffered LDS, counted-vmcnt pipeline (3 K-tiles in flight):
//   iter t: vmcnt(8)+bar [tile t landed everywhere] -> ds_read+MFMA ->
//           lgkmcnt(0)+bar [slot free] -> stage tile t+3 into slot t%3.
// Conflict-free LDS slot swizzle (verified 0 conflicts): col16B' = col16B ^
// ((row>>1)&3), applied on BOTH the stage source and the frag read.
// bn = blockIdx.x (fast) so blocks sharing an A-tile run consecutively.
// EPI 0: Hout[m][n] = f16(gelu(acc + bias[n]))
// EPI 1: Out[m][n]  = acc(main K + one fused K=32 LoRA tile Ag@Bg) + bias[n]
// ---------------------------------------------------------------------------
template <int EPI>
__global__ __launch_bounds__(512) void k_gemm256(
    const f16* __restrict__ A, const f16* __restrict__ B, int nt, int lda,
    int ldb, const float* __restrict__ bias, f16* __restrict__ Hout, int ldh,
    float* __restrict__ Out, int ldc, const f16* __restrict__ Ag,
    const f16* __restrict__ Bg) {
  __shared__ __align__(16) f16 As[3][8192];  // 3 x [256][32]
  __shared__ __align__(16) f16 Bs[3][8192];
  const int tid = threadIdx.x;
  const int lane = tid & 63;
  const int w = tid >> 6;         // 0..7
  const int wm = w >> 2;          // 0..1 (M half)
  const int wn = w & 3;           // 0..3 (N quarter)
  const int bn = blockIdx.x, bm = blockIdx.y;

  // staging addressing: thread covers local rows (tid>>2) and (tid>>2)+128,
  // 16B slot tid&3; source col XOR-swizzled by ((row>>1)&3).
  const int lrow = tid >> 2;
  const int scol = ((tid & 3) ^ ((lrow >> 1) & 3)) * 8;
  const f16* pA0 = A + (size_t)(bm * 256 + lrow) * lda + scol;
  const f16* pA1 = pA0 + (size_t)128 * lda;
  const f16* pB0 = B + (size_t)(bn * 256 + lrow) * ldb + scol;
  const f16* pB1 = pB0 + (size_t)128 * ldb;
  const f16* qA0 = nullptr; const f16* qA1 = nullptr;
  const f16* qB0 = nullptr; const f16* qB1 = nullptr;
  if constexpr (EPI == 1) {
    qA0 = Ag + (size_t)(bm * 256 + lrow) * 32 + scol;
    qA1 = qA0 + 128 * 32;
    qB0 = Bg + (size_t)(bn * 256 + lrow) * 32 + scol;
    qB1 = qB0 + 128 * 32;
  }
  // wave-uniform LDS dest base (HW adds lane*16B)
  const int dbase = w * 512;

  const int ntt = nt + (EPI == 1 ? 1 : 0);

#define STAGE(S, BUF)                                                   \
  do {                                                                  \
    f16* dA = &As[BUF][dbase];                                          \
    f16* dB = &Bs[BUF][dbase];                                          \
    if ((S) < nt) {                                                     \
      const size_t o = (size_t)(S) * 32;                                \
      glds16(pA0 + o, dA); glds16(pA1 + o, dA + 4096);                  \
      glds16(pB0 + o, dB); glds16(pB1 + o, dB + 4096);                  \
    } else {                                                            \
      glds16(qA0, dA); glds16(qA1, dA + 4096);                          \
      glds16(qB0, dB); glds16(qB1, dB + 4096);                          \
    }                                                                   \
  } while (0)

  f32x4 acc[8][4] = {};
  const int frow = lane & 15;
  const int swk = (((lane >> 4) ^ ((frow >> 1) & 3))) * 8;

#define COMPUTE(BUF)                                                        \
  do {                                                                      \
    const f16* rA = &As[BUF][(wm * 128 + frow) * 32 + swk];                 \
    const f16* rB = &Bs[BUF][(wn * 64 + frow) * 32 + swk];                  \
    f16x8 af[8], bf[4];                                                     \
    _Pragma("unroll") for (int i = 0; i < 8; i++)                           \
        af[i] = *(const f16x8*)&rA[i * 512];                                \
    _Pragma("unroll") for (int j = 0; j < 4; j++)                           \
        bf[j] = *(const f16x8*)&rB[j * 512];                                \
    _Pragma("unroll") for (int i = 0; i < 8; i++)                           \
        _Pragma("unroll") for (int j = 0; j < 4; j++)                       \
            acc[i][j] = __builtin_amdgcn_mfma_f32_16x16x32_f16(             \
                bf[j], af[i], acc[i][j], 0, 0, 0);                          \
  } while (0)

  // prologue: 3 tiles in flight
  STAGE(0, 0);
  STAGE(1, 1);
  STAGE(2, 2);

  int buf = 0;
  for (int t = 0; t < ntt - 2; ++t) {
    WAITB(8);
    COMPUTE(buf);
    DRAINB();
    if (t + 3 < ntt) STAGE(t + 3, buf);
    buf = (buf == 2) ? 0 : buf + 1;
  }
  WAITB(4);
  COMPUTE(buf);
  DRAINB();
  buf = (buf == 2) ? 0 : buf + 1;
  WAITB(0);
  COMPUTE(buf);

  // D layout (swapped operands): m = wm*128 + i*16 + (lane&15),
  // n = wn*64 + j*16 + (lane>>4)*4 + r
  const int m0 = wm * 128 + (lane & 15);
  const int n0 = wn * 64 + ((lane >> 4) << 2);

  if constexpr (EPI == 0) {
#pragma unroll
    for (int i = 0; i < 8; i++) {
      const size_t rb = (size_t)(bm * 256 + m0 + i * 16) * ldh + bn * 256 + n0;
#pragma unroll
      for (int j = 0; j < 4; j++) {
        const float4 bb = *(const float4*)&bias[bn * 256 + n0 + j * 16];
        f16x4 o = {(f16)gelu_fast(acc[i][j][0] + bb.x),
                   (f16)gelu_fast(acc[i][j][1] + bb.y),
                   (f16)gelu_fast(acc[i][j][2] + bb.z),
                   (f16)gelu_fast(acc[i][j][3] + bb.w)};
        *(f16x4*)&Hout[rb + j * 16] = o;
      }
    }
  } else {
#pragma unroll
    for (int i = 0; i < 8; i++) {
      const size_t rb = (size_t)(bm * 256 + m0 + i * 16) * ldc + bn * 256 + n0;
#pragma unroll
      for (int j = 0; j < 4; j++) {
        const float4 bb = *(const float4*)&bias[bn * 256 + n0 + j * 16];
        float4 v = {acc[i][j][0] + bb.x, acc[i][j][1] + bb.y,
                    acc[i][j][2] + bb.z, acc[i][j][3] + bb.w};
        *(float4*)&Out[rb + j * 16] = v;
      }
    }
  }
#undef STAGE
#undef COMPUTE
}

// ---------------------------------------------------------------------------
// 128x128 tile kernel, kept (proven) for the LoRA-down GEMM (EPI 2 only).
// ---------------------------------------------------------------------------
template <int EPI>
__global__ __launch_bounds__(256) void k_gemm(
    const f16* __restrict__ A, const f16* __restrict__ B, int Kt, int lda,
    int ldb, f16* __restrict__ Hout, const float* __restrict__ tkp,
    const int* __restrict__ tki) {
  __shared__ __align__(16) f16 As[2][128 * 32];
  __shared__ __align__(16) f16 Bs[2][128 * 32];
  const int tid = threadIdx.x;
  const int lane = tid & 63;
  const int w = tid >> 6;
  const int wm = w >> 1, wn = w & 1;
  const int bm = blockIdx.x, bn = blockIdx.y;

  const int c0 = 2 * w;
  const int lrow = lane >> 2;
  const int srow = c0 * 16 + lrow;
  const int skk = ((lane & 3) ^ ((lrow >> 1) & 3)) * 8;
  const f16* gA = A + (size_t)(bm * 128 + srow) * lda + skk;
  const f16* gB = B + (size_t)(bn * 128 + srow) * ldb + skk;
  f16* lA0 = &As[0][c0 * 512];
  f16* lA1 = &As[1][c0 * 512];
  f16* lB0 = &Bs[0][c0 * 512];
  f16* lB1 = &Bs[1][c0 * 512];

  f32x4 acc[4][4] = {};
  const int frow = lane & 15;
  const int swk = (((lane >> 4) ^ ((frow >> 1) & 3))) * 8;
  const int nt = Kt / 32;

  glds16(gA, lA0);
  glds16(gA + (size_t)16 * lda, lA0 + 512);
  glds16(gB, lB0);
  glds16(gB + (size_t)16 * ldb, lB0 + 512);
  __syncthreads();

  for (int t = 0; t < nt; ++t) {
    f16* dA = (t & 1) ? lA0 : lA1;
    f16* dB = (t & 1) ? lB0 : lB1;
    if (t + 1 < nt) {
      const int k = (t + 1) * 32;
      glds16(gA + k, dA);
      glds16(gA + k + (size_t)16 * lda, dA + 512);
      glds16(gB + k, dB);
      glds16(gB + k + (size_t)16 * ldb, dB + 512);
    }
    const f16* rA = As[t & 1];
    const f16* rB = Bs[t & 1];
    f16x8 af[4], bf[4];
#pragma unroll
    for (int i = 0; i < 4; i++)
      af[i] = *(const f16x8*)&rA[(wm * 64 + i * 16 + frow) * 32 + swk];
#pragma unroll
    for (int j = 0; j < 4; j++)
      bf[j] = *(const f16x8*)&rB[(wn * 64 + j * 16 + frow) * 32 + swk];
#pragma unroll
    for (int i = 0; i < 4; i++)
#pragma unroll
      for (int j = 0; j < 4; j++)
        acc[i][j] = __builtin_amdgcn_mfma_f32_16x16x32_f16(bf[j], af[i],
                                                           acc[i][j], 0, 0, 0);
    __syncthreads();
  }

  const int m0 = wm * 64 + (lane & 15);
  const int n0 = wn * 64 + ((lane >> 4) << 2);
  if (wn == 0) {
#pragma unroll
    for (int i = 0; i < 4; i++) {
      const int m = bm * 128 + m0 + i * 16;
      const int i0 = tki[m * 2], i1 = tki[m * 2 + 1];
      const float p0 = tkp[m * 2], p1 = tkp[m * 2 + 1];
#pragma unroll
      for (int j = 0; j < 2; j++) {
        const int nb = n0 + j * 16;
        const int e = nb >> 3;
        const float wgt = (i0 == e ? p0 : 0.0f) + (i1 == e ? p1 : 0.0f);
        f16x4 o = {(f16)(wgt * gelu_fast(acc[i][j][0])),
                   (f16)(wgt * gelu_fast(acc[i][j][1])),
                   (f16)(wgt * gelu_fast(acc[i][j][2])),
                   (f16)(wgt * gelu_fast(acc[i][j][3]))};
        *(f16x4*)&Hout[(size_t)m * 32 + nb] = o;
      }
    }
  }
}

extern "C" void kernel_launch(void* const* d_in, const int* in_sizes, int n_in,
                              void* d_out, int out_size, void* d_ws,
                              size_t ws_size, hipStream_t stream) {
  const float* x = (const float*)d_in[0];
  const float* W1 = (const float*)d_in[1];
  const float* b1 = (const float*)d_in[2];
  const float* W2 = (const float*)d_in[3];
  const float* b2 = (const float*)d_in[4];
  const float* wd = (const float*)d_in[5];
  const float* wu = (const float*)d_in[6];
  const float* tkp = (const float*)d_in[8];
  const int* tki = (const int*)d_in[9];
  float* out = (float*)d_out;

  const int T = in_sizes[0] / TD;  // 50176

  char* p = (char*)d_ws;
  f16* W1T = (f16*)p; p += (size_t)TDH * TD * sizeof(f16);
  f16* W2T = (f16*)p; p += (size_t)TD * TDH * sizeof(f16);
  f16* wdT = (f16*)p; p += (size_t)128 * TD * sizeof(f16);
  f16* wuT = (f16*)p; p += (size_t)TD * 32 * sizeof(f16);
  size_t fixed = (size_t)(p - (char*)d_ws);
  const size_t per_tok = (size_t)(TD + TDH + 32) * sizeof(f16);
  long mc = (long)((ws_size > fixed ? ws_size - fixed : 0) / per_tok);
  if (mc > T) mc = T;
  mc = (mc / 256) * 256;
  if (mc < 256) mc = 256;
  f16* xb = (f16*)p; p += (size_t)mc * TD * sizeof(f16);
  f16* Hb = (f16*)p; p += (size_t)mc * TDH * sizeof(f16);
  f16* gb = (f16*)p;

  k_trans<<<dim3(TDH / 32, TD / 32), dim3(32, 8), 0, stream>>>(W1T, W1, TD, TDH);
  k_trans<<<dim3(TD / 32, TDH / 32), dim3(32, 8), 0, stream>>>(W2T, W2, TDH, TD);
  k_wdT<<<dim3(65536 / 256), 256, 0, stream>>>(wdT, wd);
  k_wuT<<<dim3(16384 / 256), 256, 0, stream>>>(wuT, wu);

  for (long off = 0; off < T; off += mc) {
    long m = T - off;
    if (m > mc) m = mc;
    const int mt1 = (int)(m / 128);
    const int mt2 = (int)(m / 256);
    const int n4 = (int)(m * TD / 4);
    k_conv_x<<<dim3((n4 + 255) / 256), 256, 0, stream>>>(xb, x + off * TD, n4);
    // g[m][32] = topk-weighted gelu(x @ wd^T)
    k_gemm<2><<<dim3(mt1, 1), 256, 0, stream>>>(xb, wdT, TD, TD, TD, gb,
                                                tkp + off * 2, tki + off * 2);
    // H = gelu(x @ W1^T + b1)   (K=512 -> 16 tiles)
    k_gemm256<0><<<dim3(TDH / 256, mt2), 512, 0, stream>>>(
        xb, W1T, TD / 32, TD, TD, b1, Hb, TDH, nullptr, 0, nullptr, nullptr);
    // out = H @ W2^T + g @ wu^T + b2   (K=2048 -> 64 tiles + 1 LoRA tile)
    k_gemm256<1><<<dim3(TD / 256, mt2), 512, 0, stream>>>(
        Hb, W2T, TDH / 32, TDH, TDH, b2, nullptr, 0, out + off * TD, TD, gb,
        wuT);
  }
}

// Round 7
// 549.989 us; speedup vs baseline: 1.1315x; 1.1315x over previous
//
#include <hip/hip_runtime.h>

typedef _Float16 f16;
typedef _Float16 f16x8 __attribute__((ext_vector_type(8)));
typedef _Float16 f16x4 __attribute__((ext_vector_type(4)));
typedef float f32x4 __attribute__((ext_vector_type(4)));

#define TD 512
#define TDH 2048

// tanh-form GELU: x * sigmoid(1.595769122*x + 0.0713548162*x^3)
__device__ __forceinline__ float gelu_fast(float x) {
  float u = x * fmaf(x * x, 0.0713548162f, 1.595769122f);
  float e = __expf(-u);
  return x * __builtin_amdgcn_rcpf(1.0f + e);
}

__device__ __forceinline__ void glds16(const f16* g, f16* l) {
  __builtin_amdgcn_global_load_lds(
      (const __attribute__((address_space(1))) void*)g,
      (__attribute__((address_space(3))) void*)l, 16, 0, 0);
}

#define VW6_BAR()                                          \
  do {                                                     \
    asm volatile("s_waitcnt vmcnt(6)" ::: "memory");       \
    __builtin_amdgcn_s_barrier();                          \
  } while (0)
#define VW0_BAR()                                          \
  do {                                                     \
    asm volatile("s_waitcnt vmcnt(0)" ::: "memory");       \
    __builtin_amdgcn_s_barrier();                          \
  } while (0)
#define BAR() __builtin_amdgcn_s_barrier()
#define LGKM0() asm volatile("s_waitcnt lgkmcnt(0)" ::: "memory")

__global__ __launch_bounds__(256) void k_conv_x(f16* __restrict__ dst,
                                                const float* __restrict__ src,
                                                int n4) {
  int i = blockIdx.x * 256 + threadIdx.x;
  if (i >= n4) return;
  float4 v = ((const float4*)src)[i];
  f16x4 o = {(f16)v.x, (f16)v.y, (f16)v.z, (f16)v.w};
  ((f16x4*)dst)[i] = o;
}

// Tiled transpose: dst[c*R + r] = src[r*C + c], both sides coalesced.
__global__ void k_trans(f16* __restrict__ dst, const float* __restrict__ src,
                        int R, int C) {
  __shared__ float t[32][33];
  const int bx = blockIdx.x, by = blockIdx.y;
  const int tx = threadIdx.x, ty = threadIdx.y;
#pragma unroll
  for (int s = 0; s < 32; s += 8)
    t[ty + s][tx] = src[(size_t)(by * 32 + ty + s) * C + bx * 32 + tx];
  __syncthreads();
#pragma unroll
  for (int s = 0; s < 32; s += 8)
    dst[(size_t)(bx * 32 + ty + s) * R + by * 32 + tx] = (f16)t[tx][ty + s];
}

// wdT[128][512]: n=e*8+r for n<24 else 0 ; src wd[3][512][8]
__global__ __launch_bounds__(256) void k_wdT(f16* __restrict__ dst,
                                             const float* __restrict__ wd) {
  int i = blockIdx.x * 256 + threadIdx.x;
  int n = i >> 9, k = i & 511;
  float v = (n < 24) ? wd[(size_t)((n >> 3) * 512 + k) * 8 + (n & 7)] : 0.0f;
  dst[i] = (f16)v;
}

// wuT64[512][64]: wuT64[d][er] = wu[er/8][er%8][d] for er<24 else 0
__global__ __launch_bounds__(256) void k_wuT(f16* __restrict__ dst,
                                             const float* __restrict__ wu) {
  int i = blockIdx.x * 256 + threadIdx.x;  // 32768 total
  int d = i >> 6, er = i & 63;
  float v = (er < 24) ? wu[(size_t)(er >> 3) * 4096 + (er & 7) * 512 + d] : 0.0f;
  dst[i] = (f16)v;
}

// ---------------------------------------------------------------------------
// m201-style 8-phase 256x256 GEMM. BK=64 (2 k-halves of 32), 8 waves (2Mx4N),
// per-wave 128x64 output (8x4 frags). LDS: 2 buf x {A,B} x 2 khalf x [256][32]
// = 128KB. Per phase: ds_read subtile || stage 1 half-tile (2 glds16/thread)
// -> barrier -> lgkmcnt(0) -> setprio(1)+16 MFMA+setprio(0) -> barrier.
// vmcnt(6) only at phases 4 and 8 (3 half-tiles x 2 loads in flight).
// Stage schedule (tile pair t0=2i,t1=2i+1): ph1:(t1)B.k1  ph2:(t0+2)A.k0
// ph3:(t0+2)B.k0  ph4:(t0+2)A.k1  ph5:(t0+2)B.k1  ph6:(t1+2)A.k0
// ph7:(t1+2)B.k0  ph8:(t1+2)A.k1  -- each targets the region consumed one
// phase earlier (overwrite-safe via per-phase lgkm0+barrier).
// Conflict-free swizzle (verified 0 conflicts): 16B-slot ^= (row>>1)&3 on
// both stage source and frag read.
// Tiles with index >= ntm come from the K=64 LoRA pair (Ag stride 64, Bg).
// EPI 0: Hout[m][n] = f16(gelu(acc + bias[n]));  EPI 1: Out = acc + bias[n].
// ---------------------------------------------------------------------------
template <int EPI>
__global__ __launch_bounds__(512, 2) void k_gemm8p(
    const f16* __restrict__ A, const f16* __restrict__ B, int ntm, int NT,
    int lda, int ldb, const float* __restrict__ bias, f16* __restrict__ Hout,
    int ldh, float* __restrict__ Out, int ldc, const f16* __restrict__ Ag,
    const f16* __restrict__ Bg, int nbn) {
  __shared__ __align__(16) f16 LA[2][2][8192];  // [buf][khalf][256*32]
  __shared__ __align__(16) f16 LB[2][2][8192];
  const int tid = threadIdx.x;
  const int lane = tid & 63;
  const int w = tid >> 6;
  const int wm = w >> 2, wn = w & 3;

  // XCD-bijective swizzle (m204), bm-major ordering
  const int nwg = gridDim.x;
  const int q = nwg >> 3, r = nwg & 7;
  const int xcd = blockIdx.x & 7, pos = blockIdx.x >> 3;
  const int swz =
      (xcd < r ? xcd * (q + 1) : r * (q + 1) + (xcd - r) * q) + pos;
  const int bm = swz / nbn, bn = swz - bm * nbn;

  const int lrow = tid >> 2;
  const int scol = ((tid & 3) ^ ((lrow >> 1) & 3)) * 8;
  const f16* pA = A + (size_t)(bm * 256 + lrow) * lda + scol;
  const f16* pB = B + (size_t)(bn * 256 + lrow) * ldb + scol;
  const f16* qA =
      (EPI == 1) ? Ag + (size_t)(bm * 256 + lrow) * 64 + scol : nullptr;
  const f16* qB =
      (EPI == 1) ? Bg + (size_t)(bn * 256 + lrow) * 64 + scol : nullptr;
  const int dbase = w * 512;  // wave-uniform LDS dest (HW adds lane*16B)
  const size_t ldas = (size_t)128 * lda, ldbs = (size_t)128 * ldb;

#define STG_A(S, H, BUF)                                             \
  do {                                                               \
    if ((S) < NT) {                                                  \
      f16* d0 = &LA[BUF][H][dbase];                                  \
      if ((S) < ntm) {                                               \
        const f16* s_ = pA + (size_t)(S)*64 + (H)*32;                \
        glds16(s_, d0);                                              \
        glds16(s_ + ldas, d0 + 4096);                                \
      } else {                                                       \
        const f16* s_ = qA + (H)*32;                                 \
        glds16(s_, d0);                                              \
        glds16(s_ + 128 * 64, d0 + 4096);                            \
      }                                                              \
    }                                                                \
  } while (0)
#define STG_B(S, H, BUF)                                             \
  do {                                                               \
    if ((S) < NT) {                                                  \
      f16* d0 = &LB[BUF][H][dbase];                                  \
      if ((S) < ntm) {                                               \
        const f16* s_ = pB + (size_t)(S)*64 + (H)*32;                \
        glds16(s_, d0);                                              \
        glds16(s_ + ldbs, d0 + 4096);                                \
      } else {                                                       \
        const f16* s_ = qB + (H)*32;                                 \
        glds16(s_, d0);                                              \
        glds16(s_ + 128 * 64, d0 + 4096);                            \
      }                                                              \
    }                                                                \
  } while (0)

  f32x4 acc[8][4] = {};
  f16x8 af[8], bf[4];
  const int frow = lane & 15;
  const int swk = ((lane >> 4) ^ ((frow >> 1) & 3)) * 8;
  const int aoff = (wm * 128 + frow) * 32 + swk;  // + i*512
  const int boff = (wn * 64 + frow) * 32 + swk;   // + j*512

#define DS_AF(BUF, H)                                           \
  _Pragma("unroll") for (int i = 0; i < 8; i++) af[i] =         \
      *(const f16x8*)&LA[BUF][H][aoff + i * 512];
#define DS_BF(BUF, H, J0)                                       \
  bf[J0] = *(const f16x8*)&LB[BUF][H][boff + (J0)*512];         \
  bf[(J0) + 1] = *(const f16x8*)&LB[BUF][H][boff + ((J0) + 1) * 512];
#define MFQ(NQ)                                                         \
  __builtin_amdgcn_s_setprio(1);                                        \
  _Pragma("unroll") for (int i = 0; i < 8; i++) {                       \
    acc[i][2 * (NQ)] = __builtin_amdgcn_mfma_f32_16x16x32_f16(          \
        bf[2 * (NQ)], af[i], acc[i][2 * (NQ)], 0, 0, 0);                \
    acc[i][2 * (NQ) + 1] = __builtin_amdgcn_mfma_f32_16x16x32_f16(      \
        bf[2 * (NQ) + 1], af[i], acc[i][2 * (NQ) + 1], 0, 0, 0);        \
  }                                                                     \
  __builtin_amdgcn_s_setprio(0);

#define ITER(I, W4, W8)                                                    \
  do {                                                                     \
    const int t0 = 2 * (I), t1 = t0 + 1;                                   \
    /*ph1*/ DS_AF(0, 0); DS_BF(0, 0, 0); STG_B(t1, 1, 1);                  \
    BAR(); LGKM0(); MFQ(0); BAR();                                         \
    /*ph2*/ DS_BF(0, 0, 2); STG_A(t0 + 2, 0, 0);                           \
    BAR(); LGKM0(); MFQ(1); BAR();                                         \
    /*ph3*/ DS_AF(0, 1); DS_BF(0, 1, 0); STG_B(t0 + 2, 0, 0);              \
    BAR(); LGKM0(); MFQ(0); BAR();                                         \
    /*ph4*/ DS_BF(0, 1, 2); STG_A(t0 + 2, 1, 0);                           \
    W4(); LGKM0(); MFQ(1); BAR();                                          \
    /*ph5*/ DS_AF(1, 0); DS_BF(1, 0, 0); STG_B(t0 + 2, 1, 0);              \
    BAR(); LGKM0(); MFQ(0); BAR();                                         \
    /*ph6*/ DS_BF(1, 0, 2); STG_A(t1 + 2, 0, 1);                           \
    BAR(); LGKM0(); MFQ(1); BAR();                                         \
    /*ph7*/ DS_AF(1, 1); DS_BF(1, 1, 0); STG_B(t1 + 2, 0, 1);              \
    BAR(); LGKM0(); MFQ(0); BAR();                                         \
    /*ph8*/ DS_BF(1, 1, 2); STG_A(t1 + 2, 1, 1);                           \
    W8(); LGKM0(); MFQ(1); BAR();                                          \
  } while (0)

  // prologue: tile0 (4 halves) + tile1 (A.k0,B.k0,A.k1); vmcnt(6) -> tile0 in
  STG_A(0, 0, 0); STG_B(0, 0, 0); STG_A(0, 1, 0); STG_B(0, 1, 0);
  STG_A(1, 0, 1); STG_B(1, 0, 1); STG_A(1, 1, 1);
  VW6_BAR();

  const int NIT = NT >> 1;  // full tile pairs (EPI0: 4, EPI1: 16)
#pragma unroll 1
  for (int i = 0; i + 1 < NIT; ++i) ITER(i, VW6_BAR, VW6_BAR);
  if constexpr (EPI == 0) {
    ITER(NIT - 1, VW0_BAR, VW0_BAR);
  } else {
    ITER(NIT - 1, VW6_BAR, VW0_BAR);  // W8=vmcnt(0): tail tile fully landed
    // tail tile NT-1 (even index -> buf0), no stages, no barriers needed
    DS_AF(0, 0); DS_BF(0, 0, 0); LGKM0(); MFQ(0);
    DS_BF(0, 0, 2); LGKM0(); MFQ(1);
    DS_AF(0, 1); DS_BF(0, 1, 0); LGKM0(); MFQ(0);
    DS_BF(0, 1, 2); LGKM0(); MFQ(1);
  }

  // D layout (swapped operands, HW-verified rounds 3-5):
  // m = bm*256 + wm*128 + i*16 + (lane&15); n = bn*256 + wn*64 + j*16 +
  // (lane>>4)*4 + r
  const int m0 = wm * 128 + (lane & 15);
  const int n0 = wn * 64 + ((lane >> 4) << 2);

  if constexpr (EPI == 0) {
#pragma unroll
    for (int i = 0; i < 8; i++) {
      const size_t rb = (size_t)(bm * 256 + m0 + i * 16) * ldh + bn * 256 + n0;
#pragma unroll
      for (int j = 0; j < 4; j++) {
        const float4 bb = *(const float4*)&bias[bn * 256 + n0 + j * 16];
        f16x4 o = {(f16)gelu_fast(acc[i][j][0] + bb.x),
                   (f16)gelu_fast(acc[i][j][1] + bb.y),
                   (f16)gelu_fast(acc[i][j][2] + bb.z),
                   (f16)gelu_fast(acc[i][j][3] + bb.w)};
        *(f16x4*)&Hout[rb + j * 16] = o;
      }
    }
  } else {
#pragma unroll
    for (int i = 0; i < 8; i++) {
      const size_t rb = (size_t)(bm * 256 + m0 + i * 16) * ldc + bn * 256 + n0;
#pragma unroll
      for (int j = 0; j < 4; j++) {
        const float4 bb = *(const float4*)&bias[bn * 256 + n0 + j * 16];
        float4 v = {acc[i][j][0] + bb.x, acc[i][j][1] + bb.y,
                    acc[i][j][2] + bb.z, acc[i][j][3] + bb.w};
        *(float4*)&Out[rb + j * 16] = v;
      }
    }
  }
#undef STG_A
#undef STG_B
#undef DS_AF
#undef DS_BF
#undef MFQ
#undef ITER
}

// ---------------------------------------------------------------------------
// 128x128 2-phase kernel (proven) for the LoRA-down GEMM.
// g[m][64]: cols 0..31 = topk_w * gelu(x @ wdT), cols 32..63 = 0.
// ---------------------------------------------------------------------------
__global__ __launch_bounds__(256) void k_lora_down(
    const f16* __restrict__ A, const f16* __restrict__ B, int Kt, int lda,
    int ldb, f16* __restrict__ Gout, const float* __restrict__ tkp,
    const int* __restrict__ tki) {
  __shared__ __align__(16) f16 As[2][128 * 32];
  __shared__ __align__(16) f16 Bs[2][128 * 32];
  const int tid = threadIdx.x;
  const int lane = tid & 63;
  const int w = tid >> 6;
  const int wm = w >> 1, wn = w & 1;
  const int bm = blockIdx.x;

  const int c0 = 2 * w;
  const int lrow = lane >> 2;
  const int srow = c0 * 16 + lrow;
  const int skk = ((lane & 3) ^ ((lrow >> 1) & 3)) * 8;
  const f16* gA = A + (size_t)(bm * 128 + srow) * lda + skk;
  const f16* gB = B + (size_t)srow * ldb + skk;
  f16* lA0 = &As[0][c0 * 512];
  f16* lA1 = &As[1][c0 * 512];
  f16* lB0 = &Bs[0][c0 * 512];
  f16* lB1 = &Bs[1][c0 * 512];

  f32x4 acc[4][4] = {};
  const int frow = lane & 15;
  const int swk = ((lane >> 4) ^ ((frow >> 1) & 3)) * 8;
  const int nt = Kt / 32;

  glds16(gA, lA0);
  glds16(gA + (size_t)16 * lda, lA0 + 512);
  glds16(gB, lB0);
  glds16(gB + (size_t)16 * ldb, lB0 + 512);
  __syncthreads();

  for (int t = 0; t < nt; ++t) {
    f16* dA = (t & 1) ? lA0 : lA1;
    f16* dB = (t & 1) ? lB0 : lB1;
    if (t + 1 < nt) {
      const int k = (t + 1) * 32;
      glds16(gA + k, dA);
      glds16(gA + k + (size_t)16 * lda, dA + 512);
      glds16(gB + k, dB);
      glds16(gB + k + (size_t)16 * ldb, dB + 512);
    }
    const f16* rA = As[t & 1];
    const f16* rB = Bs[t & 1];
    f16x8 af[4], bf[4];
#pragma unroll
    for (int i = 0; i < 4; i++)
      af[i] = *(const f16x8*)&rA[(wm * 64 + i * 16 + frow) * 32 + swk];
#pragma unroll
    for (int j = 0; j < 4; j++)
      bf[j] = *(const f16x8*)&rB[(wn * 64 + j * 16 + frow) * 32 + swk];
#pragma unroll
    for (int i = 0; i < 4; i++)
#pragma unroll
      for (int j = 0; j < 4; j++)
        acc[i][j] = __builtin_amdgcn_mfma_f32_16x16x32_f16(bf[j], af[i],
                                                           acc[i][j], 0, 0, 0);
    __syncthreads();
  }

  const int m0 = wm * 64 + (lane & 15);
  const int n0 = wn * 64 + ((lane >> 4) << 2);
  if (wn == 0) {
#pragma unroll
    for (int i = 0; i < 4; i++) {
      const int m = bm * 128 + m0 + i * 16;
      const int i0 = tki[m * 2], i1 = tki[m * 2 + 1];
      const float p0 = tkp[m * 2], p1 = tkp[m * 2 + 1];
#pragma unroll
      for (int j = 0; j < 2; j++) {
        const int nb = n0 + j * 16;  // 0..28
        const int e = nb >> 3;
        const float wgt = (i0 == e ? p0 : 0.0f) + (i1 == e ? p1 : 0.0f);
        f16x4 o = {(f16)(wgt * gelu_fast(acc[i][j][0])),
                   (f16)(wgt * gelu_fast(acc[i][j][1])),
                   (f16)(wgt * gelu_fast(acc[i][j][2])),
                   (f16)(wgt * gelu_fast(acc[i][j][3]))};
        *(f16x4*)&Gout[(size_t)m * 64 + nb] = o;
        f16x4 z = {(f16)0.f, (f16)0.f, (f16)0.f, (f16)0.f};
        *(f16x4*)&Gout[(size_t)m * 64 + nb + 32] = z;  // K-pad zeros
      }
    }
  }
}

extern "C" void kernel_launch(void* const* d_in, const int* in_sizes, int n_in,
                              void* d_out, int out_size, void* d_ws,
                              size_t ws_size, hipStream_t stream) {
  const float* x = (const float*)d_in[0];
  const float* W1 = (const float*)d_in[1];
  const float* b1 = (const float*)d_in[2];
  const float* W2 = (const float*)d_in[3];
  const float* b2 = (const float*)d_in[4];
  const float* wd = (const float*)d_in[5];
  const float* wu = (const float*)d_in[6];
  const float* tkp = (const float*)d_in[8];
  const int* tki = (const int*)d_in[9];
  float* out = (float*)d_out;

  const int T = in_sizes[0] / TD;  // 50176

  char* p = (char*)d_ws;
  f16* W1T = (f16*)p; p += (size_t)TDH * TD * sizeof(f16);
  f16* W2T = (f16*)p; p += (size_t)TD * TDH * sizeof(f16);
  f16* wdT = (f16*)p; p += (size_t)128 * TD * sizeof(f16);
  f16* wuT = (f16*)p; p += (size_t)TD * 64 * sizeof(f16);  // K-padded to 64
  size_t fixed = (size_t)(p - (char*)d_ws);
  const size_t per_tok = (size_t)(TD + TDH + 64) * sizeof(f16);
  long mc = (long)((ws_size > fixed ? ws_size - fixed : 0) / per_tok);
  if (mc > T) mc = T;
  mc = (mc / 256) * 256;
  if (mc < 256) mc = 256;
  f16* xb = (f16*)p; p += (size_t)mc * TD * sizeof(f16);
  f16* Hb = (f16*)p; p += (size_t)mc * TDH * sizeof(f16);
  f16* gb = (f16*)p;  // [mc][64]

  k_trans<<<dim3(TDH / 32, TD / 32), dim3(32, 8), 0, stream>>>(W1T, W1, TD,
                                                               TDH);
  k_trans<<<dim3(TD / 32, TDH / 32), dim3(32, 8), 0, stream>>>(W2T, W2, TDH,
                                                               TD);
  k_wdT<<<dim3(65536 / 256), 256, 0, stream>>>(wdT, wd);
  k_wuT<<<dim3(32768 / 256), 256, 0, stream>>>(wuT, wu);

  for (long off = 0; off < T; off += mc) {
    long m = T - off;
    if (m > mc) m = mc;
    const int mt1 = (int)(m / 128);
    const int mt2 = (int)(m / 256);
    const int n4 = (int)(m * TD / 4);
    k_conv_x<<<dim3((n4 + 255) / 256), 256, 0, stream>>>(xb, x + off * TD, n4);
    // g[m][64] = topk-weighted gelu(x @ wd^T) | zeros  (K=512)
    k_lora_down<<<dim3(mt1), 256, 0, stream>>>(xb, wdT, TD, TD, TD, gb,
                                               tkp + off * 2, tki + off * 2);
    // H = gelu(x @ W1^T + b1)   (K=512 -> 8 BK64 tiles)
    k_gemm8p<0><<<dim3(mt2 * (TDH / 256)), 512, 0, stream>>>(
        xb, W1T, TD / 64, TD / 64, TD, TD, b1, Hb, TDH, nullptr, 0, nullptr,
        nullptr, TDH / 256);
    // out = H @ W2^T + g @ wu64^T + b2  (32 main BK64 tiles + 1 LoRA tile)
    k_gemm8p<1><<<dim3(mt2 * (TD / 256)), 512, 0, stream>>>(
        Hb, W2T, TDH / 64, TDH / 64 + 1, TDH, TDH, b2, nullptr, 0,
        out + off * TD, TD, gb, wuT, TD / 256);
  }
}